// Round 10
// baseline (148.673 us; speedup 1.0000x reference)
//
#include <hip/hip_runtime.h>
#include <hip/hip_bf16.h>

// MANN fused v6: 4 plain launches, NO separate W-conversion pass.
// B=512, IN=480, OUT=400, HID=512, K=8.
// Evidence r6/r7: dur_us carries ~100us of harness-fixed overhead (256MiB
// workspace poison fills ~43us each inside the timed graph: coop kernel
// measured 350.7us/dispatch vs dur_us 452.9). Our controllable budget is
// ~35-45us across 4 kernels + gaps. v5's biggest dead weight: the fp32->bf16
// W conversion passes (k_phase0 read ALL 22.8MB fp32 W; cvt_units tails in
// k1/k2; Wb round-trip = 11.4MB writes + re-reads).
// v6 = cvt-on-stage: each layer stages its W directly from fp32 via
// regs (issued one window early, T14 split) -> RNE cvt -> ds_write_b128 into
// the SAME XOR-swizzled LDS layout (consumer unchanged). Layer1 reads x fp32
// and cvts A-frags in-register (same RNE bits as the old xbf). Wb1/2/3 and
// xbf buffers eliminated; k0 = gating only. Numerics bitwise-identical to
// v5/baseline (expect absmax exactly 0.0009765625).
// Predicted: our-kernel WRITE_SIZE 13.5 -> ~2MB; dur 139.8 -> 122-132us.
// (Rounds 8-9 were GPUAcquisitionTimeouts -- identical resubmission.)

typedef __hip_bfloat16 bf16;
typedef unsigned short u16;
typedef __attribute__((ext_vector_type(8))) short bf16x8;
typedef __attribute__((ext_vector_type(4))) float f32x4;

__device__ __forceinline__ float elu1(float x) { return x > 0.f ? x : expm1f(x); }

__device__ __forceinline__ u16 cvt1(float v) {
    union { bf16 h; u16 u; } c;
    c.h = __float2bfloat16(v);          // RNE
    return c.u;
}

// ---------------- kernel 0: gating MLP only ----------------
__global__ __launch_bounds__(256) void k_gating(
    const float* __restrict__ x, const int* __restrict__ idx_raw,
    const float* __restrict__ GW1, const float* __restrict__ Gb1,
    const float* __restrict__ GW2, const float* __restrict__ Gb2,
    const float* __restrict__ GW3, const float* __restrict__ Gb3,
    float* __restrict__ gout)
{
    __shared__ float xg[32];
    __shared__ float h1[128];
    __shared__ float h2[128];
    const int b = blockIdx.x;
    const int j = threadIdx.x;

    if (j < 32) {
        // gating_idx may arrive as int32 or int64; word1==0 iff int64
        int ii;
        if (idx_raw[1] == 0) ii = (int)((const long long*)idx_raw)[j];
        else                 ii = idx_raw[j];
        if (ii < 0 || ii >= 480) ii = 448 + j;  // memory-safety clamp
        xg[j] = x[(size_t)b * 480 + ii];
    }
    __syncthreads();

    if (j < 128) {
        float a = Gb1[j];
        #pragma unroll
        for (int i = 0; i < 32; ++i) a += xg[i] * GW1[i * 128 + j];
        h1[j] = elu1(a);
    }
    __syncthreads();

    if (j < 128) {
        float a2 = Gb2[j];
        #pragma unroll 8
        for (int i = 0; i < 128; ++i) a2 += h1[i] * GW2[i * 128 + j];
        h2[j] = elu1(a2);
    }
    __syncthreads();

    if (j < 8) {
        float a3 = Gb3[j];
        for (int i = 0; i < 128; ++i) a3 += h2[i] * GW3[i * 8 + j];
        gout[b * 8 + j] = a3;                // no activation on blend coeffs
    }
}

// out[b,o] = act( sum_k g[b,k] * ( sum_i A[b,i]*Wk[k,o,i] + bk[k,o] ) )
// block: o-tile 16 (bid&31) x m-tile 32 (bid>>5). Blocks sharing an o-tile
// land on one XCD (bid%8 = o%8) -> fp32 W tile is L2-local, read 16x.
// W staged fp32->bf16 on the fly: thread owns 16B LDS slots L = q*256+tid;
// slot (r, c8) holds global chunk c = c8 ^ (r&7) (XOR swizzle on the source
// side, LDS write linear) so the ds_read_b128 B-frag path is unchanged.
template <int IDIM, int ODIM, bool ELU, bool AF32, typename OutT>
__global__ __launch_bounds__(256, 2) void k_layer(
    const void* __restrict__ Aptr,  // [512, IDIM] bf16 (or fp32 if AF32)
    const float* __restrict__ Wf,   // [8, ODIM, IDIM] fp32
    const float* __restrict__ bk,   // [8, ODIM] fp32
    const float* __restrict__ gv,   // [512, 8] fp32
    OutT* __restrict__ out)         // [512, ODIM]
{
    constexpr int KW = 64;                       // K-window (halfwords)
    constexpr int NW = (IDIM + KW - 1) / KW;     // 8 windows
    __shared__ u16 wbuf[2][128 * KW];            // 2 x 16 KB -> 2 blocks/CU
    const int bid = blockIdx.x;
    const int o0 = (bid & 31) * 16;
    if (o0 >= ODIM) return;                      // ODIM=400: uniform per block
    const int m0  = (bid >> 5) * 32;
    const int tid = threadIdx.x;
    const int wid = tid >> 6, lane = tid & 63;
    const int n = lane & 15, quad = lane >> 4;
    const int e0 = wid * 2;                      // wave expert-pair

    // per-thread staging map (window-independent part)
    size_t rowoff[4]; int coff[4];
    #pragma unroll
    for (int q = 0; q < 4; ++q) {
        const int L = q * 256 + tid;
        const int r = L >> 3, c8 = L & 7;        // r = e*16+nr
        const int e = r >> 4, nr = r & 15;
        rowoff[q] = (size_t)(e * ODIM + o0 + nr) * IDIM;
        coff[q]   = (c8 ^ (nr & 7)) * 8;         // global chunk for this slot
    }
    // issue global fp32 loads for window w (T14 issue-early)
    auto issue = [&](int w, float4 (&f)[4][2]) {
        #pragma unroll
        for (int q = 0; q < 4; ++q) {
            int koff = w * KW + coff[q];
            if (koff + 8 > IDIM) koff = IDIM - 8;   // clamp; never consumed
            const float* p = Wf + rowoff[q] + koff;
            f[q][0] = *(const float4*)p;
            f[q][1] = *(const float4*)(p + 4);
        }
    };
    // cvt + ds_write (write-late; compiler inserts the vmcnt wait)
    auto commit = [&](float4 (&f)[4][2], u16* buf) {
        #pragma unroll
        for (int q = 0; q < 4; ++q) {
            union { u16 h[8]; uint4 v; } o;
            o.h[0] = cvt1(f[q][0].x); o.h[1] = cvt1(f[q][0].y);
            o.h[2] = cvt1(f[q][0].z); o.h[3] = cvt1(f[q][0].w);
            o.h[4] = cvt1(f[q][1].x); o.h[5] = cvt1(f[q][1].y);
            o.h[6] = cvt1(f[q][1].z); o.h[7] = cvt1(f[q][1].w);
            *(uint4*)(buf + (size_t)(q * 256 + tid) * 8) = o.v;
        }
    };

    const f32x4 zero = {0.f, 0.f, 0.f, 0.f};
    f32x4 acc[2][2] = {{zero, zero}, {zero, zero}};
    float4 fa[4][2], fb[4][2];                   // ping-pong staging regs

    issue(0, fa);
    commit(fa, wbuf[0]);
    issue(1, fb);
    __syncthreads();                             // buf0 visible

    #pragma unroll
    for (int w = 0; w < NW; ++w) {
        u16* cur = wbuf[w & 1];
        u16* nxt = wbuf[(w + 1) & 1];
        // write W(w+1) into the buffer last read in iter w-1 (barrier-safe),
        // then issue W(w+2) so its latency hides under MFMA + barrier.
        if (w + 1 < NW) { if (w & 1) commit(fa, nxt); else commit(fb, nxt); }
        if (w + 2 < NW) { if (w & 1) issue(w + 2, fb); else issue(w + 2, fa); }
        #pragma unroll
        for (int cl = 0; cl < 2; ++cl) {
            const int i0 = w * KW + cl * 32;
            if (i0 >= IDIM) break;               // trims last window (480)
            bf16x8 af[2];
            #pragma unroll
            for (int s = 0; s < 2; ++s) {
                if constexpr (AF32) {
                    const float* ap = (const float*)Aptr
                        + (size_t)(m0 + 16 * s + n) * IDIM + i0 + quad * 8;
                    float4 u = *(const float4*)ap;
                    float4 v = *(const float4*)(ap + 4);
                    union { u16 h[8]; bf16x8 b; } t;
                    t.h[0] = cvt1(u.x); t.h[1] = cvt1(u.y);
                    t.h[2] = cvt1(u.z); t.h[3] = cvt1(u.w);
                    t.h[4] = cvt1(v.x); t.h[5] = cvt1(v.y);
                    t.h[6] = cvt1(v.z); t.h[7] = cvt1(v.w);
                    af[s] = t.b;
                } else {
                    af[s] = *(const bf16x8*)((const u16*)Aptr
                        + (size_t)(m0 + 16 * s + n) * IDIM + i0 + quad * 8);
                }
            }
            const int sl = ((cl * 4 + quad) ^ (n & 7)) * 8;
            #pragma unroll
            for (int jj = 0; jj < 2; ++jj) {
                bf16x8 bfr = *(const bf16x8*)(cur + ((e0 + jj) * 16 + n) * KW + sl);
                acc[0][jj] = __builtin_amdgcn_mfma_f32_16x16x32_bf16(af[0], bfr, acc[0][jj], 0, 0, 0);
                acc[1][jj] = __builtin_amdgcn_mfma_f32_16x16x32_bf16(af[1], bfr, acc[1][jj], 0, 0, 0);
            }
        }
        __syncthreads();             // W(w+1) visible; cur reads done
    }

    // ---- epilogue: each wave blends its 2 experts; 4 planes summed via LDS.
    // C/D layout: col = lane&15 (=n), row = quad*4 + reg (batch).
    float* part = (float*)&wbuf[0][0];   // [4][32][17] fp32, 8.7 KB
    float bkv[2];
    #pragma unroll
    for (int jj = 0; jj < 2; ++jj) bkv[jj] = bk[(e0 + jj) * ODIM + o0 + n];

    #pragma unroll
    for (int s = 0; s < 2; ++s) {
        #pragma unroll
        for (int r = 0; r < 4; ++r) {
            const int lrow = 16 * s + 4 * quad + r;
            const int grow = m0 + lrow;
            float v = 0.f;
            #pragma unroll
            for (int jj = 0; jj < 2; ++jj)
                v += gv[grow * 8 + e0 + jj] * (acc[s][jj][r] + bkv[jj]);
            part[(wid * 32 + lrow) * 17 + n] = v;
        }
    }
    __syncthreads();

    #pragma unroll
    for (int rr = 0; rr < 2; ++rr) {
        const int lrow = rr * 16 + (tid >> 4);
        const int col  = tid & 15;
        float v = part[lrow * 17 + col] + part[(32 + lrow) * 17 + col]
                + part[(64 + lrow) * 17 + col] + part[(96 + lrow) * 17 + col];
        if (ELU) v = elu1(v);
        if constexpr (__hip_internal::is_same<OutT, float>::value)
            out[(size_t)(m0 + lrow) * ODIM + o0 + col] = v;
        else
            out[(size_t)(m0 + lrow) * ODIM + o0 + col] = cvt1(v);
    }
}

extern "C" void kernel_launch(void* const* d_in, const int* in_sizes, int n_in,
                              void* d_out, int out_size, void* d_ws, size_t ws_size,
                              hipStream_t stream)
{
    const float* x   = (const float*)d_in[0];
    const int* gidx  = (const int*)d_in[1];
    const float* GW1 = (const float*)d_in[2];
    const float* Gb1 = (const float*)d_in[3];
    const float* GW2 = (const float*)d_in[4];
    const float* Gb2 = (const float*)d_in[5];
    const float* GW3 = (const float*)d_in[6];
    const float* Gb3 = (const float*)d_in[7];
    const float* Wk1 = (const float*)d_in[8];
    const float* bk1 = (const float*)d_in[9];
    const float* Wk2 = (const float*)d_in[10];
    const float* bk2 = (const float*)d_in[11];
    const float* Wk3 = (const float*)d_in[12];
    const float* bk3 = (const float*)d_in[13];

    char* ws  = (char*)d_ws;
    float* g  = (float*)ws;                          // @0      (16 KB)
    u16* A1   = (u16*)(ws + (1 << 20));              // @1 MB   (512 KB)
    u16* A2   = (u16*)(ws + (1 << 20) + (512 << 10));// @1.5 MB (512 KB)

    k_gating<<<512, 256, 0, stream>>>(x, gidx, GW1, Gb1, GW2, Gb2,
                                      GW3, Gb3, g);
    k_layer<480, 512, true,  true,  u16> <<<512, 256, 0, stream>>>(
        x,  Wk1, bk1, g, A1);
    k_layer<512, 512, true,  false, u16> <<<512, 256, 0, stream>>>(
        A1, Wk2, bk2, g, A2);
    k_layer<512, 400, false, false, float><<<512, 256, 0, stream>>>(
        A2, Wk3, bk3, g, (float*)d_out);
}

// Round 11
// 133.387 us; speedup vs baseline: 1.1146x; 1.1146x over previous
//
#include <hip/hip_runtime.h>
#include <hip/hip_bf16.h>

// MANN fused v7: baseline v3 structure (133.0us known-good) with ONE change:
// W2/W3 fp32->bf16 conversion deferred from k0 into the tails of L1/L2.
// B=512, IN=480, OUT=400, HID=512, K=8.
// Ladder evidence: baseline(m64/KW128/gload_lds, cvt upfront)=133.0 <
// v5(m32/KW64, cvt tails)=139.8 < v6(m32/KW64/reg-stage fp32)=148.7, and
// coop grid.sync=452.9. The op is launch/latency-bound (~100us harness-fixed
// poison fills + ~33us ours); traffic cuts don't pay, barrier-count and
// gload_lds staging do. KW=128 (4 windows/layer) and 1 block/CU are kept.
// v7 delta: k0 reads only W1 (7.5MB not 22.8MB); W2 cvt (1024 units/block)
// streams in L1's tail, W3 cvt (800 units/block) in L2's tail -- overlapping
// the straggler drain instead of serializing ahead of all MFMA work.
// Predicted: dur 133.0 -> 127-131us; absmax exactly 0.0009765625.

typedef __hip_bfloat16 bf16;
typedef unsigned short u16;
typedef __attribute__((ext_vector_type(8))) short bf16x8;
typedef __attribute__((ext_vector_type(4))) float f32x4;

__device__ __forceinline__ float elu1(float x) { return x > 0.f ? x : expm1f(x); }

__device__ __forceinline__ u16 cvt1(float v) {
    union { bf16 h; u16 u; } c;
    c.h = __float2bfloat16(v);          // RNE
    return c.u;
}

__device__ __forceinline__ void async16(const u16* g, u16* l) {
    __builtin_amdgcn_global_load_lds(
        (const __attribute__((address_space(1))) void*)g,
        (__attribute__((address_space(3))) void*)l, 16, 0, 0);
}

// fp32 -> bf16, NU 8-elem units per block (block b owns units [b*NU,(b+1)*NU))
template <int NU>
__device__ __forceinline__ void cvt_units(const float* __restrict__ src,
                                          u16* __restrict__ dst, int b, int tid)
{
    #pragma unroll
    for (int jj = 0; jj < (NU + 255) / 256; ++jj) {
        const int local = jj * 256 + tid;
        if ((NU & 255) && local >= NU) break;
        const size_t off = ((size_t)b * NU + local) * 8;
        float4 a = *(const float4*)(src + off);
        float4 c = *(const float4*)(src + off + 4);
        union { u16 h[8]; uint4 v; } o;
        o.h[0] = cvt1(a.x); o.h[1] = cvt1(a.y); o.h[2] = cvt1(a.z); o.h[3] = cvt1(a.w);
        o.h[4] = cvt1(c.x); o.h[5] = cvt1(c.y); o.h[6] = cvt1(c.z); o.h[7] = cvt1(c.w);
        *(uint4*)(dst + off) = o.v;
    }
}

// ---------------- kernel 0: gating MLP + x-cvt + W1-cvt ----------------
__global__ __launch_bounds__(256) void gating_cvt_kernel(
    const float* __restrict__ x, const int* __restrict__ idx_raw,
    const float* __restrict__ GW1, const float* __restrict__ Gb1,
    const float* __restrict__ GW2, const float* __restrict__ Gb2,
    const float* __restrict__ GW3, const float* __restrict__ Gb3,
    const float* __restrict__ Wk1,
    float* __restrict__ g, u16* __restrict__ xbf, u16* __restrict__ Wb1)
{
    __shared__ float xg[32];
    __shared__ float h1[128];
    __shared__ float h2[128];
    const int b = blockIdx.x;
    const int j = threadIdx.x;

    if (j < 32) {
        // gating_idx may arrive as int32 or int64; word1==0 iff int64
        int ii;
        if (idx_raw[1] == 0) ii = (int)((const long long*)idx_raw)[j];
        else                 ii = idx_raw[j];
        if (ii < 0 || ii >= 480) ii = 448 + j;  // memory-safety clamp
        xg[j] = x[(size_t)b * 480 + ii];
    }
    __syncthreads();

    if (j < 128) {
        float a = Gb1[j];
        #pragma unroll
        for (int i = 0; i < 32; ++i) a += xg[i] * GW1[i * 128 + j];
        h1[j] = elu1(a);
    }
    __syncthreads();

    if (j < 128) {
        float a2 = Gb2[j];
        #pragma unroll 8
        for (int i = 0; i < 128; ++i) a2 += h1[i] * GW2[i * 128 + j];
        h2[j] = elu1(a2);
    }
    __syncthreads();

    if (j < 8) {
        float a3 = Gb3[j];
        for (int i = 0; i < 128; ++i) a3 += h2[i] * GW3[i * 8 + j];
        g[b * 8 + j] = a3;  // no activation on blend coefficients
    }

    // x -> bf16 (this block's row)
    for (int i = j; i < 480; i += 256)
        xbf[b * 480 + i] = cvt1(x[b * 480 + i]);

    // W1 -> bf16 only: 245760 units / 512 blocks = 480 units/block.
    cvt_units<480>(Wk1, Wb1, b, j);
}

// ---------------- fused blended layer (baseline tiling, verbatim) ----------
// out[b,o] = act( sum_k g[b,k] * ( sum_i A[b,i]*Wk[k,o,i] + bk[k,o] ) )
// block = o-tile 16 x m-tile 64 (grid 256 = 32 o x 8 m). W staged to LDS via
// global_load_lds width=16 (async, no staging VGPRs). LDS dest linear; XOR
// swizzle applied on the GLOBAL address side: LDS slot (r,slot) holds global
// chunk c = slot ^ (r&7) so ds_read_b128 B-frags hit uniform bank residues.
// K-windows of 128, 2x32KB double buffer. Wave tile = 2 m-subtiles x 4
// experts -> 8 MFMA per cl. Epilogue blends experts in-block via LDS.
// NU_NEXT > 0: after the layer, this kernel's blocks stream the NEXT layer's
// fp32->bf16 W conversion (overlaps the straggler drain).
template <int IDIM, int ODIM, bool ELU, typename OutT, int NU_NEXT>
__global__ __launch_bounds__(256) void layer_kernel(
    const u16*  __restrict__ A,    // [512, IDIM] bf16
    const u16*  __restrict__ Wb,   // [8, ODIM, IDIM] bf16
    const float* __restrict__ bk,  // [8, ODIM] fp32
    const float* __restrict__ g,   // [512, 8] fp32
    OutT* __restrict__ out,        // [512, ODIM]
    const float* __restrict__ Wnext_src, u16* __restrict__ Wnext_dst)
{
    constexpr int KW = 128;                       // K-window (halfwords)
    constexpr int NW = (IDIM + KW - 1) / KW;      // 4 for IDIM=480 and 512
    __shared__ u16 wbuf[2][128 * KW];             // 2 x 32 KB

    const int ot = blockIdx.x & 31;
    const int o0 = ot * 16;
    if (o0 < ODIM) {                              // ODIM=400: ot>=25 layer-idle
    const int m0   = (blockIdx.x >> 5) * 64;
    const int tid  = threadIdx.x;
    const int wid  = tid >> 6;
    const int lane = tid & 63;
    const int n    = lane & 15;    // out col within tile / A row within 16
    const int quad = lane >> 4;
    const int w_m  = wid & 1;      // wave m-half (rows m0+32*w_m .. +31)
    const int e0   = (wid >> 1) * 4;  // wave expert-quad

    // ---- async staging: 32 KB/window = 8 global_load_lds per wave.
    // instr t fills 16B-slots L = (wid*8+t)*64 + lane; L -> r=L>>4 (=e*16+nr),
    // slot=L&15; that slot holds global chunk c = slot ^ (nr&7). ----
    auto stage = [&](int w, u16* buf) {
        const int w0 = w * KW;
        #pragma unroll
        for (int t = 0; t < 8; ++t) {
            const int L = (wid * 8 + t) * 64 + lane;
            const int r = L >> 4, slot = L & 15;
            const int e = r >> 4, nr = r & 15;
            int koff = w0 + (slot ^ (nr & 7)) * 8;
            if (koff + 8 > IDIM) koff = IDIM - 8;   // clamp; never read
            async16(Wb + ((size_t)(e * ODIM + o0 + nr)) * IDIM + koff,
                    (u16*)buf + (size_t)(wid * 8 + t) * 512);
        }
    };

    const f32x4 zero = {0.f, 0.f, 0.f, 0.f};
    f32x4 acc[2][4] = {{zero, zero, zero, zero}, {zero, zero, zero, zero}};

    stage(0, wbuf[0]);
    __syncthreads();                 // barrier implies vmcnt(0) drain

    for (int w = 0; w < NW; ++w) {
        if (w + 1 < NW) stage(w + 1, wbuf[(w + 1) & 1]);  // in flight under MFMA

        const u16* buf = wbuf[w & 1];
        #pragma unroll
        for (int cl = 0; cl < KW / 32; ++cl) {
            const int i0 = w * KW + cl * 32;
            if (i0 >= IDIM) break;           // trims last window (IDIM=480)
            bf16x8 af[2];
            #pragma unroll
            for (int s = 0; s < 2; ++s)
                af[s] = *(const bf16x8*)(A + (size_t)(m0 + 16 * (2 * w_m + s) + n) * IDIM
                                           + i0 + quad * 8);
            const int cw = cl * 4 + quad;
            const int slot = (cw ^ (n & 7)) * 8;
            #pragma unroll
            for (int j = 0; j < 4; ++j) {
                bf16x8 bfr = *(const bf16x8*)(buf + ((e0 + j) * 16 + n) * KW + slot);
                acc[0][j] = __builtin_amdgcn_mfma_f32_16x16x32_bf16(af[0], bfr, acc[0][j], 0, 0, 0);
                acc[1][j] = __builtin_amdgcn_mfma_f32_16x16x32_bf16(af[1], bfr, acc[1][j], 0, 0, 0);
            }
        }
        __syncthreads();             // drains stage(w+1) + protects reuse
    }

    // ---- epilogue: wave blends its 4 experts; halves summed via LDS ----
    // C/D layout: col = lane&15 (=n), row = quad*4 + reg (batch).
    float* part = (float*)wbuf;              // [2][64][17] fp32, 8.7 KB
    float bkv[4];
    #pragma unroll
    for (int j = 0; j < 4; ++j) bkv[j] = bk[(e0 + j) * ODIM + o0 + n];

    #pragma unroll
    for (int s = 0; s < 2; ++s) {
        #pragma unroll
        for (int r = 0; r < 4; ++r) {
            const int lrow = 16 * (2 * w_m + s) + 4 * quad + r;
            const int grow = m0 + lrow;
            float v = 0.f;
            #pragma unroll
            for (int j = 0; j < 4; ++j)
                v += g[grow * 8 + e0 + j] * (acc[s][j][r] + bkv[j]);
            part[((wid >> 1) * 64 + lrow) * 17 + n] = v;
        }
    }
    __syncthreads();

    #pragma unroll
    for (int rr = 0; rr < 4; ++rr) {
        const int lrow = 16 * wid + 4 * quad + rr;
        float v = part[lrow * 17 + n] + part[(64 + lrow) * 17 + n];
        if (ELU) v = elu1(v);
        const int grow = m0 + lrow;
        if constexpr (__hip_internal::is_same<OutT, float>::value)
            out[(size_t)grow * ODIM + o0 + n] = v;
        else
            out[(size_t)grow * ODIM + o0 + n] = cvt1(v);
    }
    }  // end if (o0 < ODIM)

    // ---- tail: stream next layer's W fp32->bf16 (overlaps drain) ----
    if constexpr (NU_NEXT > 0)
        cvt_units<NU_NEXT>(Wnext_src, Wnext_dst, blockIdx.x, threadIdx.x);
}

extern "C" void kernel_launch(void* const* d_in, const int* in_sizes, int n_in,
                              void* d_out, int out_size, void* d_ws, size_t ws_size,
                              hipStream_t stream)
{
    const float* x   = (const float*)d_in[0];
    const int* gidx  = (const int*)d_in[1];
    const float* GW1 = (const float*)d_in[2];
    const float* Gb1 = (const float*)d_in[3];
    const float* GW2 = (const float*)d_in[4];
    const float* Gb2 = (const float*)d_in[5];
    const float* GW3 = (const float*)d_in[6];
    const float* Gb3 = (const float*)d_in[7];
    const float* Wk1 = (const float*)d_in[8];
    const float* bk1 = (const float*)d_in[9];
    const float* Wk2 = (const float*)d_in[10];
    const float* bk2 = (const float*)d_in[11];
    const float* Wk3 = (const float*)d_in[12];
    const float* bk3 = (const float*)d_in[13];

    char* ws  = (char*)d_ws;
    float* g  = (float*)ws;                          // @0      (16 KB)
    u16* xbf  = (u16*)(ws + (64 << 10));             // @64 KB  (480 KB)
    u16* A1   = (u16*)(ws + (1 << 20));              // @1 MB   (512 KB)
    u16* A2   = (u16*)(ws + (1 << 20) + (512 << 10));// @1.5 MB (512 KB)
    u16* Wb1  = (u16*)(ws + (2 << 20));              // @2 MB   (3.75 MB)
    u16* Wb2  = (u16*)(ws + (6 << 20));              // @6 MB   (4 MB)
    u16* Wb3  = (u16*)(ws + (10 << 20));             // @10 MB  (3.13 MB)

    // k0: gating + x-cvt + W1-cvt (512 blocks, 480 units/block)
    gating_cvt_kernel<<<512, 256, 0, stream>>>(x, gidx, GW1, Gb1, GW2, Gb2,
                                               GW3, Gb3, Wk1, g, xbf, Wb1);
    // L1 + W2-cvt tail (256 blocks: 262144/256 = 1024 units/block)
    layer_kernel<480, 512, true,  u16,  1024><<<256, 256, 0, stream>>>(
        xbf, Wb1, bk1, g, A1, Wk2, Wb2);
    // L2 + W3-cvt tail (204800/256 = 800 units/block)
    layer_kernel<512, 512, true,  u16,  800><<<256, 256, 0, stream>>>(
        A1,  Wb2, bk2, g, A2, Wk3, Wb3);
    // L3 (fp32 out, no tail)
    layer_kernel<512, 400, false, float, 0><<<256, 256, 0, stream>>>(
        A2,  Wb3, bk3, g, (float*)d_out, (const float*)nullptr, (u16*)nullptr);
}